// Round 2
// baseline (239.388 us; speedup 1.0000x reference)
//
#include <hip/hip_runtime.h>
#include <math.h>

#define EPS 1e-05

static constexpr int BLOCK  = 256;
static constexpr int BPB    = 768;   // blocks per batch
static constexpr int KPT    = 9;     // float4s per thread per stream (768*256*9 = 192^3/4)
static constexpr int NBATCH = 4;
static constexpr long long NPB = 192LL * 192LL * 192LL; // 7,077,888 elems/batch

typedef float v4f __attribute__((ext_vector_type(4)));

__device__ __forceinline__ double wave_reduce(double v) {
    #pragma unroll
    for (int off = 32; off > 0; off >>= 1)
        v += __shfl_down(v, off, 64);
    return v;
}

__global__ __launch_bounds__(BLOCK, 4) void ncc_partial(
    const float* __restrict__ y_pred, const float* __restrict__ y_true,
    double* __restrict__ part)
{
    const int b  = blockIdx.y;
    const int bx = blockIdx.x;
    const v4f* __restrict__ I4 = (const v4f*)(y_true + (long long)b * NPB);
    const v4f* __restrict__ J4 = (const v4f*)(y_pred + (long long)b * NPB);

    // 32-bit indexing: max float4 index 1,769,471 -> byte offset < 28.4 MB.
    // SAME index for both streams (pairing required for IJ_sum — do NOT
    // decorrelate the two streams).
    const unsigned base = (unsigned)bx * (BLOCK * KPT) + threadIdx.x;

    // Packed f32 vector accumulators; converted to f64 once below
    // (cc error ~1e-9 vs 4.1e-6 threshold).
    v4f vI  = {0.f, 0.f, 0.f, 0.f};
    v4f vJ  = {0.f, 0.f, 0.f, 0.f};
    v4f vI2 = {0.f, 0.f, 0.f, 0.f};
    v4f vJ2 = {0.f, 0.f, 0.f, 0.f};
    v4f vIJ = {0.f, 0.f, 0.f, 0.f};

    #pragma unroll
    for (int k = 0; k < KPT; ++k) {
        // PLAIN loads (R2 change): the harness's input-restore copies run
        // right before this kernel and leave the 226.5 MB input set largely
        // L3-resident (copyBuffer fetched only 56.6/113 MB from HBM).
        // Non-temporal loads were forfeiting those hits — single-variable
        // A/B vs R1: NT -> cached.
        v4f a = I4[base + k * BLOCK];
        v4f c = J4[base + k * BLOCK];
        vI  += a;
        vJ  += c;
        vI2 += a * a;
        vJ2 += c * c;
        vIJ += a * c;
    }

    // Horizontal combine in f64 (once per thread).
    double sI  = ((double)vI.x  + (double)vI.y)  + ((double)vI.z  + (double)vI.w);
    double sJ  = ((double)vJ.x  + (double)vJ.y)  + ((double)vJ.z  + (double)vJ.w);
    double sI2 = ((double)vI2.x + (double)vI2.y) + ((double)vI2.z + (double)vI2.w);
    double sJ2 = ((double)vJ2.x + (double)vJ2.y) + ((double)vJ2.z + (double)vJ2.w);
    double sIJ = ((double)vIJ.x + (double)vIJ.y) + ((double)vIJ.z + (double)vIJ.w);

    sI  = wave_reduce(sI);
    sJ  = wave_reduce(sJ);
    sI2 = wave_reduce(sI2);
    sJ2 = wave_reduce(sJ2);
    sIJ = wave_reduce(sIJ);

    __shared__ double lds[BLOCK / 64][5];
    const int wave = threadIdx.x >> 6;
    const int lane = threadIdx.x & 63;
    if (lane == 0) {
        lds[wave][0] = sI;  lds[wave][1] = sJ;
        lds[wave][2] = sI2; lds[wave][3] = sJ2;
        lds[wave][4] = sIJ;
    }
    __syncthreads();
    if (threadIdx.x == 0) {
        double* p = part + ((long long)b * BPB + bx) * 5;
        #pragma unroll
        for (int k = 0; k < 5; ++k)
            p[k] = ((lds[0][k] + lds[1][k]) + (lds[2][k] + lds[3][k]));
    }
}

__global__ __launch_bounds__(BLOCK) void ncc_final(
    const double* __restrict__ part, float* __restrict__ out)
{
    const int b = blockIdx.x;
    // BPB/BLOCK partial sets per thread.
    double s[5] = {0.0, 0.0, 0.0, 0.0, 0.0};
    #pragma unroll
    for (int j = 0; j < BPB / BLOCK; ++j) {
        const double* p = part + ((long long)b * BPB + j * BLOCK + threadIdx.x) * 5;
        #pragma unroll
        for (int k = 0; k < 5; ++k) s[k] += p[k];
    }
    #pragma unroll
    for (int k = 0; k < 5; ++k) s[k] = wave_reduce(s[k]);

    __shared__ double lds[BLOCK / 64][5];
    const int wave = threadIdx.x >> 6;
    const int lane = threadIdx.x & 63;
    if (lane == 0) {
        #pragma unroll
        for (int k = 0; k < 5; ++k) lds[wave][k] = s[k];
    }
    __syncthreads();
    if (threadIdx.x == 0) {
        double I_sum  = (lds[0][0] + lds[1][0]) + (lds[2][0] + lds[3][0]);
        double J_sum  = (lds[0][1] + lds[1][1]) + (lds[2][1] + lds[3][1]);
        double I2_sum = (lds[0][2] + lds[1][2]) + (lds[2][2] + lds[3][2]);
        double J2_sum = (lds[0][3] + lds[1][3]) + (lds[2][3] + lds[3][3]);
        double IJ_sum = (lds[0][4] + lds[1][4]) + (lds[2][4] + lds[3][4]);

        const double win = (double)NPB;
        const double u_I = I_sum / win;
        const double u_J = J_sum / win;
        const double cross = IJ_sum - u_J * I_sum - u_I * J_sum + u_I * u_J * win;
        const double I_var = I2_sum - 2.0 * u_I * I_sum + u_I * u_I * win;
        const double J_var = J2_sum - 2.0 * u_J * J_sum + u_J * u_J * win;
        const double cc = cross / (sqrt(I_var) * sqrt(J_var) + EPS);
        out[b] = (float)cc;
    }
}

extern "C" void kernel_launch(void* const* d_in, const int* in_sizes, int n_in,
                              void* d_out, int out_size, void* d_ws, size_t ws_size,
                              hipStream_t stream) {
    // setup_inputs order: y_pred, y_true. reference(y_pred, y_true): Ii=y_true, Ji=y_pred.
    const float* y_pred = (const float*)d_in[0];
    const float* y_true = (const float*)d_in[1];
    float* out = (float*)d_out;
    double* part = (double*)d_ws;   // 4 * 768 * 5 * 8 B = 120 KB

    dim3 grid1(BPB, NBATCH);
    ncc_partial<<<grid1, BLOCK, 0, stream>>>(y_pred, y_true, part);
    ncc_final<<<NBATCH, BLOCK, 0, stream>>>(part, out);
}

// Round 3
// 216.193 us; speedup vs baseline: 1.1073x; 1.1073x over previous
//
#include <hip/hip_runtime.h>
#include <math.h>
#include <utility>

#define EPS 1e-05

static constexpr int BLOCK  = 256;
static constexpr int BPB    = 256;   // blocks per batch -> grid 1024 = 256 CU x 4 blocks/CU
static constexpr int DEPTH  = 4;     // LDS ring slots (double^2 buffer)
static constexpr int TILES  = 27;    // 27 tiles x 4096 B x 256 blocks = 192^3*4 B per stream
static constexpr int NBATCH = 4;
static constexpr long long NPB = 192LL * 192LL * 192LL; // elems per batch per stream
static constexpr int TILE_BYTES  = BLOCK * 16;          // 4096 B per stream per tile
static constexpr int BLOCK_BYTES = TILES * TILE_BYTES;  // 110,592 B per stream per block

typedef float v4f __attribute__((ext_vector_type(4)));

__device__ __forceinline__ double wave_reduce(double v) {
    #pragma unroll
    for (int off = 32; off > 0; off >>= 1)
        v += __shfl_down(v, off, 64);
    return v;
}

// Async global->LDS stage, 16B/lane, NT cache policy (aux bit1 = NT on gfx940+;
// keeps the R0/R1-proven non-temporal read path — R2 showed cached reads are
// SLOWER even with 50% L3 hits).
__device__ __forceinline__ void stage(const void* g, void* l) {
    __builtin_amdgcn_global_load_lds((const unsigned int*)g, (unsigned int*)l,
                                     16, 0, 2);
}

// One pipeline step: wait for tile T's two staged loads (counted vmcnt, never
// 0 in steady state), consume own-wave LDS slot, then re-stage tile T+DEPTH
// into the slot just freed. No __syncthreads in the loop: each wave reads only
// the LDS it staged itself.
template <int T>
__device__ __forceinline__ void tile_step(
    const char* bI, const char* bJ,
    v4f (*lI)[BLOCK], v4f (*lJ)[BLOCK],
    unsigned tid, unsigned wave,
    v4f& vI, v4f& vJ, v4f& vI2, v4f& vJ2, v4f& vIJ)
{
    constexpr int rem  = TILES - 1 - T;                 // tiles still issued after T
    constexpr int WAIT = (2 * rem < 2 * (DEPTH - 1)) ? 2 * rem : 2 * (DEPTH - 1);
    asm volatile("s_waitcnt vmcnt(%0)" :: "i"(WAIT) : "memory");

    constexpr int d = T % DEPTH;
    v4f a = lI[d][tid];
    v4f c = lJ[d][tid];
    vI  += a;
    vJ  += c;
    vI2 += a * a;
    vJ2 += c * c;
    vIJ += a * c;

    if constexpr (T + DEPTH < TILES) {
        // ds_reads above must retire before their slot is overwritten.
        asm volatile("s_waitcnt lgkmcnt(0)" ::: "memory");
        stage(bI + (T + DEPTH) * TILE_BYTES + tid * 16, &lI[d][wave << 6]);
        stage(bJ + (T + DEPTH) * TILE_BYTES + tid * 16, &lJ[d][wave << 6]);
    }
}

template <int... Ts>
__device__ __forceinline__ void run_tiles(
    std::integer_sequence<int, Ts...>,
    const char* bI, const char* bJ,
    v4f (*lI)[BLOCK], v4f (*lJ)[BLOCK],
    unsigned tid, unsigned wave,
    v4f& vI, v4f& vJ, v4f& vI2, v4f& vJ2, v4f& vIJ)
{
    (tile_step<Ts>(bI, bJ, lI, lJ, tid, wave, vI, vJ, vI2, vJ2, vIJ), ...);
}

__global__ __launch_bounds__(BLOCK) void ncc_partial(
    const float* __restrict__ y_pred, const float* __restrict__ y_true,
    double* __restrict__ part)
{
    __shared__ v4f ldsI[DEPTH][BLOCK];   // 16 KiB
    __shared__ v4f ldsJ[DEPTH][BLOCK];   // 16 KiB
    __shared__ double red[BLOCK / 64][5];

    const int b  = blockIdx.y;
    const int bx = blockIdx.x;
    const unsigned tid  = threadIdx.x;
    const unsigned wave = tid >> 6;

    // SAME offsets for both streams (pairing required for IJ_sum).
    const char* bI = (const char*)(y_true + (long long)b * NPB) + (long long)bx * BLOCK_BYTES;
    const char* bJ = (const char*)(y_pred + (long long)b * NPB) + (long long)bx * BLOCK_BYTES;

    // Prologue: fill the ring — 2*DEPTH = 8 loads in flight per wave
    // (8 KiB/wave; ~128 KiB in flight per CU at 16 waves/CU — decoupled from
    // VGPR budget, which is what the R0/R1 VGPR-held pipelines couldn't do).
    #pragma unroll
    for (int d = 0; d < DEPTH; ++d) {
        stage(bI + d * TILE_BYTES + tid * 16, &ldsI[d][wave << 6]);
        stage(bJ + d * TILE_BYTES + tid * 16, &ldsJ[d][wave << 6]);
    }

    v4f vI  = {0.f, 0.f, 0.f, 0.f};
    v4f vJ  = {0.f, 0.f, 0.f, 0.f};
    v4f vI2 = {0.f, 0.f, 0.f, 0.f};
    v4f vJ2 = {0.f, 0.f, 0.f, 0.f};
    v4f vIJ = {0.f, 0.f, 0.f, 0.f};

    run_tiles(std::make_integer_sequence<int, TILES>{},
              bI, bJ, ldsI, ldsJ, tid, wave, vI, vJ, vI2, vJ2, vIJ);

    // Horizontal combine in f64 (once per thread; cc error ~1e-9 vs 4.1e-6).
    double sI  = ((double)vI.x  + (double)vI.y)  + ((double)vI.z  + (double)vI.w);
    double sJ  = ((double)vJ.x  + (double)vJ.y)  + ((double)vJ.z  + (double)vJ.w);
    double sI2 = ((double)vI2.x + (double)vI2.y) + ((double)vI2.z + (double)vI2.w);
    double sJ2 = ((double)vJ2.x + (double)vJ2.y) + ((double)vJ2.z + (double)vJ2.w);
    double sIJ = ((double)vIJ.x + (double)vIJ.y) + ((double)vIJ.z + (double)vIJ.w);

    sI  = wave_reduce(sI);
    sJ  = wave_reduce(sJ);
    sI2 = wave_reduce(sI2);
    sJ2 = wave_reduce(sJ2);
    sIJ = wave_reduce(sIJ);

    const int lane = tid & 63;
    if (lane == 0) {
        red[wave][0] = sI;  red[wave][1] = sJ;
        red[wave][2] = sI2; red[wave][3] = sJ2;
        red[wave][4] = sIJ;
    }
    __syncthreads();
    if (tid == 0) {
        double* p = part + ((long long)b * BPB + bx) * 5;
        #pragma unroll
        for (int k = 0; k < 5; ++k)
            p[k] = ((red[0][k] + red[1][k]) + (red[2][k] + red[3][k]));
    }
}

__global__ __launch_bounds__(BLOCK) void ncc_final(
    const double* __restrict__ part, float* __restrict__ out)
{
    const int b = blockIdx.x;
    // One partial set per thread (BPB == BLOCK == 256).
    const double* p = part + ((long long)b * BPB + threadIdx.x) * 5;
    double s[5];
    #pragma unroll
    for (int k = 0; k < 5; ++k) s[k] = p[k];
    #pragma unroll
    for (int k = 0; k < 5; ++k) s[k] = wave_reduce(s[k]);

    __shared__ double lds[BLOCK / 64][5];
    const int wave = threadIdx.x >> 6;
    const int lane = threadIdx.x & 63;
    if (lane == 0) {
        #pragma unroll
        for (int k = 0; k < 5; ++k) lds[wave][k] = s[k];
    }
    __syncthreads();
    if (threadIdx.x == 0) {
        double I_sum  = (lds[0][0] + lds[1][0]) + (lds[2][0] + lds[3][0]);
        double J_sum  = (lds[0][1] + lds[1][1]) + (lds[2][1] + lds[3][1]);
        double I2_sum = (lds[0][2] + lds[1][2]) + (lds[2][2] + lds[3][2]);
        double J2_sum = (lds[0][3] + lds[1][3]) + (lds[2][3] + lds[3][3]);
        double IJ_sum = (lds[0][4] + lds[1][4]) + (lds[2][4] + lds[3][4]);

        const double win = (double)NPB;
        const double u_I = I_sum / win;
        const double u_J = J_sum / win;
        const double cross = IJ_sum - u_J * I_sum - u_I * J_sum + u_I * u_J * win;
        const double I_var = I2_sum - 2.0 * u_I * I_sum + u_I * u_I * win;
        const double J_var = J2_sum - 2.0 * u_J * J_sum + u_J * u_J * win;
        const double cc = cross / (sqrt(I_var) * sqrt(J_var) + EPS);
        out[b] = (float)cc;
    }
}

extern "C" void kernel_launch(void* const* d_in, const int* in_sizes, int n_in,
                              void* d_out, int out_size, void* d_ws, size_t ws_size,
                              hipStream_t stream) {
    // setup_inputs order: y_pred, y_true. reference(y_pred, y_true): Ii=y_true, Ji=y_pred.
    const float* y_pred = (const float*)d_in[0];
    const float* y_true = (const float*)d_in[1];
    float* out = (float*)d_out;
    double* part = (double*)d_ws;   // 4 * 256 * 5 * 8 B = 40 KB

    dim3 grid1(BPB, NBATCH);
    ncc_partial<<<grid1, BLOCK, 0, stream>>>(y_pred, y_true, part);
    ncc_final<<<NBATCH, BLOCK, 0, stream>>>(part, out);
}